// Round 13
// baseline (1305.121 us; speedup 1.0000x reference)
//
#include <hip/hip_runtime.h>

#define N_NODES 100000
#define N_EDGES 600000
#define NGRAPH 512
#define NOPS_T 8
#define EPS_MSG 1e-7f
#define EPS_LN 1e-5f

typedef unsigned short u16;
typedef unsigned int u32;
typedef __attribute__((ext_vector_type(8))) short short8;   // 8 bf16 (4 VGPRs) MFMA A/B frag
typedef __attribute__((ext_vector_type(4))) float f32x4;    // MFMA C/D frag

__device__ __forceinline__ float bf2f(u16 u) {
    union { float f; u32 i; } v; v.i = ((u32)u) << 16; return v.f;
}
__device__ __forceinline__ u16 f2bf(float f) {
    union { float f; u32 i; } v; v.f = f;
    u32 r = (v.i + 0x7fffu + ((v.i >> 16) & 1u)) >> 16;   // RNE
    return (u16)r;
}
__device__ __forceinline__ float wave_sum(float v) {
    #pragma unroll
    for (int off = 32; off > 0; off >>= 1) v += __shfl_xor(v, off, 64);
    return v;
}

// =============== encoder: h2 = bf16(x @ We + be) ===============
__global__ __launch_bounds__(256, 1) void k_enc(const float* __restrict__ x,
                                                const float* __restrict__ We,
                                                const float* __restrict__ be,
                                                u16* __restrict__ h2) {
    __shared__ __align__(16) u16 sWe[128 * 136];   // We^T padded (+8): row n, k contiguous
    __shared__ float sB[128];
    int tid = threadIdx.x;
    for (int i = tid; i < 128 * 128; i += 256) { int k = i >> 7, n = i & 127; sWe[n * 136 + k] = f2bf(We[i]); }
    if (tid < 128) sB[tid] = be[tid];
    __syncthreads();
    int wave = tid >> 6, lane = tid & 63, q = lane >> 4, c = lane & 15;
    for (int tile = blockIdx.x * 4 + wave; tile < N_NODES / 16; tile += gridDim.x * 4) {
        int n0 = tile * 16;
        const float4* xp = (const float4*)(x + (size_t)(n0 + c) * 128);
        short8 af[4];
        #pragma unroll
        for (int ks = 0; ks < 4; ks++) {
            float4 v0 = xp[ks * 8 + q * 2], v1 = xp[ks * 8 + q * 2 + 1];
            short8 a;
            a[0] = (short)f2bf(v0.x); a[1] = (short)f2bf(v0.y);
            a[2] = (short)f2bf(v0.z); a[3] = (short)f2bf(v0.w);
            a[4] = (short)f2bf(v1.x); a[5] = (short)f2bf(v1.y);
            a[6] = (short)f2bf(v1.z); a[7] = (short)f2bf(v1.w);
            af[ks] = a;
        }
        f32x4 acc[8];
        #pragma unroll
        for (int t = 0; t < 8; t++) {
            f32x4 a4 = {0.f, 0.f, 0.f, 0.f};
            const short8* bp = (const short8*)(sWe + (t * 16 + c) * 136);
            #pragma unroll
            for (int ks = 0; ks < 4; ks++)
                a4 = __builtin_amdgcn_mfma_f32_16x16x32_bf16(af[ks], bp[ks * 4 + q], a4, 0, 0, 0);
            acc[t] = a4;
        }
        u16* h2b = h2 + (size_t)n0 * 128;
        #pragma unroll
        for (int t = 0; t < 8; t++)
            #pragma unroll
            for (int i = 0; i < 4; i++) {
                int idx = (q * 4 + i) * 128 + t * 16 + c;     // D: row=q*4+i, col=t*16+c
                h2b[idx] = f2bf(acc[t][i] + sB[t * 16 + c]);
            }
    }
}

// =============== weight pre-convert: fp32 -> bf16 transposed (n-major, k-contig) ===============
__global__ __launch_bounds__(256) void k_wconv(const float* __restrict__ W1,
                                               const float* __restrict__ W2,
                                               u16* __restrict__ w1t,
                                               u16* __restrict__ w2t) {
    int b = blockIdx.x, t = threadIdx.x;
    if (b < 512) {
        int idx = b * 256 + t;                           // over [4][256][128]
        int l = idx >> 15, r = idx & 32767, n = r >> 7, k = r & 127;
        w1t[idx] = f2bf(W1[(l << 15) + k * 256 + n]);
    } else {
        int idx = (b - 512) * 256 + t;                   // over [4][128][256]
        int l = idx >> 15, r = idx & 32767, n = r >> 8, k = r & 255;
        w2t[idx] = f2bf(W2[(l << 15) + k * 128 + n]);
    }
}

// =============== CSR build (once per launch; edges static across layers) ===============
__global__ __launch_bounds__(256) void k_hist(const int* __restrict__ ei, int* __restrict__ deg) {
    int e = blockIdx.x * 256 + threadIdx.x;
    if (e < N_EDGES) atomicAdd(&deg[ei[N_EDGES + e]], 1);
}

__global__ __launch_bounds__(256) void k_scan1(const int* __restrict__ deg,
                                               int* __restrict__ offs,
                                               int* __restrict__ bsum) {
    __shared__ int swv[4];
    int b = blockIdx.x, t = threadIdx.x;
    int base = b * 1024 + t * 4;
    int4 v = {0, 0, 0, 0};
    if (base < N_NODES) v = *(const int4*)(deg + base);   // N_NODES % 4 == 0
    int s = v.x + v.y + v.z + v.w;
    int lane = t & 63, wid = t >> 6;
    int incl = s;
    #pragma unroll
    for (int off = 1; off < 64; off <<= 1) {
        int o = __shfl_up(incl, off, 64);
        if (lane >= off) incl += o;
    }
    if (lane == 63) swv[wid] = incl;
    __syncthreads();
    int wbase = 0;
    #pragma unroll
    for (int w = 0; w < 4; w++) if (w < wid) wbase += swv[w];
    int ex = wbase + incl - s;
    if (base < N_NODES) {
        offs[base]     = ex;
        offs[base + 1] = ex + v.x;
        offs[base + 2] = ex + v.x + v.y;
        offs[base + 3] = ex + v.x + v.y + v.z;
    }
    if (t == 255) bsum[b] = wbase + incl;
}

__global__ __launch_bounds__(128) void k_scan2(int* __restrict__ bsum, int nb) {
    __shared__ int s[128];
    int t = threadIdx.x;
    int v = t < nb ? bsum[t] : 0;
    s[t] = v;
    __syncthreads();
    for (int off = 1; off < 128; off <<= 1) {
        int a = t >= off ? s[t - off] : 0;
        __syncthreads();
        s[t] += a;
        __syncthreads();
    }
    if (t < nb) bsum[t] = s[t] - v;
}

__global__ __launch_bounds__(256) void k_scan3(int* __restrict__ offs,
                                               const int* __restrict__ bsum,
                                               int* __restrict__ cursor) {
    int b = blockIdx.x, t = threadIdx.x;
    int base = b * 1024 + t * 4;
    if (base >= N_NODES) return;
    int add = bsum[b];
    #pragma unroll
    for (int i = 0; i < 4; i++) {
        int o = offs[base + i] + add;
        offs[base + i] = o;
        cursor[base + i] = o;
    }
}

__global__ __launch_bounds__(256) void k_scatter(const int* __restrict__ ei,
                                                 const int* __restrict__ ea,
                                                 int* __restrict__ cursor,
                                                 int* __restrict__ csr) {
    int e = blockIdx.x * 256 + threadIdx.x;
    if (e >= N_EDGES) return;
    int s = ei[e], d = ei[N_EDGES + e], a = ea[e];
    int pos = atomicAdd(&cursor[d], 1);
    csr[pos] = s | (a << 24);                 // src < 2^17, attr < 8
}

// =============== degree bucket-sort: perm groups near-equal-degree nodes per tile ===============
__global__ __launch_bounds__(256) void k_dhist(const int* __restrict__ deg, int* __restrict__ dhist) {
    int n = blockIdx.x * 256 + threadIdx.x;
    if (n < N_NODES) atomicAdd(&dhist[min(deg[n], 63)], 1);
}
__global__ __launch_bounds__(64) void k_dscan(int* __restrict__ dhist) {
    int t = threadIdx.x;
    int v = dhist[t];
    int incl = v;
    #pragma unroll
    for (int off = 1; off < 64; off <<= 1) {
        int o = __shfl_up(incl, off, 64);
        if (t >= off) incl += o;
    }
    dhist[t] = incl - v;                      // exclusive prefix -> bucket cursor
}
__global__ __launch_bounds__(256) void k_dplace(const int* __restrict__ deg,
                                                int* __restrict__ dhist,
                                                int* __restrict__ perm) {
    int n = blockIdx.x * 256 + threadIdx.x;
    if (n < N_NODES) {
        int pos = atomicAdd(&dhist[min(deg[n], 63)], 1);
        perm[pos] = n;
    }
}

// =============== fused layer: AGG + GEMM1 + LN + ReLU + GEMM2 (+resid) + epilogue ===============
// v11: = R10/R12 best build + degree-sorted tile assignment. Tile t processes nodes
// perm[t*16..+15] (near-equal degrees), so the lockstep edge loop runs ~avg-degree
// iterations instead of max-of-16 (~2x fewer gather latency steps, no divergence).
// All arrays stay in original-node-id layout; only tile->node ownership changes.
// 512 thr, 1 block/CU, LDS 154.2 KB, no reg cap (2 waves/SIMD hard ceiling: every
// 4-wave/SIMD attempt spilled — R4/R7/R11).
__global__ __launch_bounds__(512, 1) void k_fused(
    const u16* __restrict__ h2_in, float* __restrict__ h,
    const u16* __restrict__ w1t, const float* __restrict__ b1,
    const float* __restrict__ g1, const float* __restrict__ bb1,
    const u16* __restrict__ w2t, const float* __restrict__ b2,
    const float* __restrict__ gno, const float* __restrict__ bno,
    u16* __restrict__ h2_out, const int* __restrict__ batch,
    const int* __restrict__ offs, const int* __restrict__ deg,
    const int* __restrict__ csr, const float* __restrict__ Et,
    const int* __restrict__ perm,
    float* __restrict__ pool, float* __restrict__ cnt,
    int resid, int do_pool) {
    __shared__ __align__(16) u16 sW1[256 * 136];   // W1^T: [n][k], +8 pad      69632 B
    __shared__ __align__(16) u16 sW2[128 * 264];   // W2^T: [n][k], +8 pad      67584 B
    __shared__ __align__(16) u16 sY[8][16 * 40];   // per-wave y staging        10240 B
    __shared__ __align__(16) u16 sEb[8 * 136];     // Et bf16, +8 pad            2176 B
    __shared__ float sP[1152];                     // b1|g1|bb1|b2|gno|bno       4608 B
    int tid = threadIdx.x;
    {   // vectorized weight staging (16B load -> ds_write_b128)
        const short8* w1v = (const short8*)w1t;    // chunk i = n*16 + kc
        for (int i = tid; i < 4096; i += 512) { int n = i >> 4, kc = i & 15; *((short8*)(sW1 + n * 136) + kc) = w1v[i]; }
        const short8* w2v = (const short8*)w2t;    // chunk i = n*32 + kc
        for (int i = tid; i < 4096; i += 512) { int n = i >> 5, kc = i & 31; *((short8*)(sW2 + n * 264) + kc) = w2v[i]; }
    }
    for (int i = tid; i < 1024; i += 512) { int a = i >> 7, d = i & 127; sEb[a * 136 + d] = f2bf(Et[i]); }
    if (tid < 256) { sP[tid] = b1[tid]; sP[256 + tid] = g1[tid]; sP[512 + tid] = bb1[tid]; }
    if (tid < 128) { sP[768 + tid] = b2[tid]; sP[896 + tid] = gno[tid]; sP[1024 + tid] = bno[tid]; }
    __syncthreads();

    int wave = tid >> 6, lane = tid & 63, q = lane >> 4, c = lane & 15;
    u16* yst = sY[wave];
    const int NT = N_NODES / 16;

    for (int tile = blockIdx.x * 8 + wave; tile < NT; tile += gridDim.x * 8) {
        int n0 = tile * 16;
        int n = perm[n0 + c];                          // node this lane-group processes
        // row nodes for D-layout rows q*4+i (resid / store addressing)
        int nr[4];
        #pragma unroll
        for (int i = 0; i < 4; i++) nr[i] = perm[n0 + q * 4 + i];
        // ---- fused aggregation: ag[ks][e] covers dims ks*32+q*8+e of node n ----
        float ag[4][8];
        {
            const short8* sp = (const short8*)(h2_in + (size_t)n * 128);
            #pragma unroll
            for (int ks = 0; ks < 4; ks++) {
                short8 sv = sp[ks * 4 + q];
                #pragma unroll
                for (int e = 0; e < 8; e++) ag[ks][e] = bf2f((u16)sv[e]);
            }
        }
        int st = offs[n], dgv = deg[n];
        int j = 0;
        for (; j + 1 < dgv; j += 2) {                 // unroll-2: two gathers in flight
            int p0 = csr[st + j], p1 = csr[st + j + 1];
            int s0 = p0 & 0xFFFFFF, a0 = ((u32)p0) >> 24;
            int s1 = p1 & 0xFFFFFF, a1 = ((u32)p1) >> 24;
            const short8* h0 = (const short8*)(h2_in + (size_t)s0 * 128);
            const short8* h1 = (const short8*)(h2_in + (size_t)s1 * 128);
            short8 hv0[4], hv1[4], ev0[4], ev1[4];
            #pragma unroll
            for (int ks = 0; ks < 4; ks++) {
                hv0[ks] = h0[ks * 4 + q];
                hv1[ks] = h1[ks * 4 + q];
                ev0[ks] = *(const short8*)(sEb + a0 * 136 + ks * 32 + q * 8);
                ev1[ks] = *(const short8*)(sEb + a1 * 136 + ks * 32 + q * 8);
            }
            #pragma unroll
            for (int ks = 0; ks < 4; ks++)
                #pragma unroll
                for (int e = 0; e < 8; e++) {
                    ag[ks][e] += fmaxf(bf2f((u16)hv0[ks][e]) + bf2f((u16)ev0[ks][e]), 0.f) + EPS_MSG;
                    ag[ks][e] += fmaxf(bf2f((u16)hv1[ks][e]) + bf2f((u16)ev1[ks][e]), 0.f) + EPS_MSG;
                }
        }
        if (j < dgv) {
            int p = csr[st + j];
            int s = p & 0xFFFFFF, a = ((u32)p) >> 24;
            const short8* h0 = (const short8*)(h2_in + (size_t)s * 128);
            #pragma unroll
            for (int ks = 0; ks < 4; ks++) {
                short8 hv = h0[ks * 4 + q];
                short8 ev = *(const short8*)(sEb + a * 136 + ks * 32 + q * 8);
                #pragma unroll
                for (int e = 0; e < 8; e++)
                    ag[ks][e] += fmaxf(bf2f((u16)hv[e]) + bf2f((u16)ev[e]), 0.f) + EPS_MSG;
            }
        }
        // ---- pack A fragments (bf16) ----
        short8 af[4];
        #pragma unroll
        for (int ks = 0; ks < 4; ks++) {
            short8 a;
            #pragma unroll
            for (int e = 0; e < 8; e++) a[e] = (short)f2bf(ag[ks][e]);
            af[ks] = a;
        }
        // ---- residual load (issues now; hides under GEMM1+LN1+GEMM2) ----
        float rr[8][4];
        if (resid) {
            #pragma unroll
            for (int t2 = 0; t2 < 8; t2++)
                #pragma unroll
                for (int i = 0; i < 4; i++) rr[t2][i] = h[(size_t)nr[i] * 128 + t2 * 16 + c];
        } else {
            #pragma unroll
            for (int t2 = 0; t2 < 8; t2++)
                #pragma unroll
                for (int i = 0; i < 4; i++) rr[t2][i] = 0.f;
        }
        // ---- GEMM1 ----
        f32x4 acc[16];
        #pragma unroll
        for (int t = 0; t < 16; t++) {
            f32x4 a4 = {0.f, 0.f, 0.f, 0.f};
            const short8* bp = (const short8*)(sW1 + (t * 16 + c) * 136);
            #pragma unroll
            for (int ks = 0; ks < 4; ks++)
                a4 = __builtin_amdgcn_mfma_f32_16x16x32_bf16(af[ks], bp[ks * 4 + q], a4, 0, 0, 0);
            acc[t] = a4;
        }
        // ---- +b1, LN over 256, ReLU (in-register; rows live in one quad) ----
        float sm[4] = {0, 0, 0, 0}, sq[4] = {0, 0, 0, 0};
        #pragma unroll
        for (int t = 0; t < 16; t++)
            #pragma unroll
            for (int i = 0; i < 4; i++) {
                float v = acc[t][i] + sP[t * 16 + c];
                acc[t][i] = v; sm[i] += v; sq[i] += v * v;
            }
        #pragma unroll
        for (int i = 0; i < 4; i++)
            #pragma unroll
            for (int m = 1; m < 16; m <<= 1) { sm[i] += __shfl_xor(sm[i], m, 64); sq[i] += __shfl_xor(sq[i], m, 64); }
        float mean[4], rs[4];
        #pragma unroll
        for (int i = 0; i < 4; i++) {
            mean[i] = sm[i] * (1.f / 256.f);
            float var = fmaxf(sq[i] * (1.f / 256.f) - mean[i] * mean[i], 0.f);
            rs[i] = rsqrtf(var + EPS_LN);
        }
        #pragma unroll
        for (int t = 0; t < 16; t++)
            #pragma unroll
            for (int i = 0; i < 4; i++) {
                int nn = t * 16 + c;
                acc[t][i] = fmaxf(sP[256 + nn] * (acc[t][i] - mean[i]) * rs[i] + sP[512 + nn], 0.f);
            }
        // ---- GEMM2: 8 K=32 chunks, single-buffer; read m -> stage m+1 -> MFMA m ----
        f32x4 acc2[8];
        #pragma unroll
        for (int t2 = 0; t2 < 8; t2++) acc2[t2] = (f32x4){0.f, 0.f, 0.f, 0.f};
        #pragma unroll
        for (int tt = 0; tt < 2; tt++)
            #pragma unroll
            for (int i = 0; i < 4; i++)
                yst[(q * 4 + i) * 40 + tt * 16 + c] = f2bf(acc[tt][i]);
        #pragma unroll
        for (int m = 0; m < 8; m++) {
            short8 a2 = *(const short8*)(yst + c * 40 + q * 8);   // read chunk m
            if (m < 7) {   // stage chunk m+1 while chunk m computes
                #pragma unroll
                for (int tt = 0; tt < 2; tt++)
                    #pragma unroll
                    for (int i = 0; i < 4; i++)
                        yst[(q * 4 + i) * 40 + tt * 16 + c] = f2bf(acc[(m + 1) * 2 + tt][i]);
            }
            #pragma unroll
            for (int t2 = 0; t2 < 8; t2++) {
                const short8* bp2 = (const short8*)(sW2 + (t2 * 16 + c) * 264 + m * 32);
                acc2[t2] = __builtin_amdgcn_mfma_f32_16x16x32_bf16(a2, bp2[q], acc2[t2], 0, 0, 0);
            }
        }
        // ---- epilogue: +b2 (+resid), then LN over 128 ----
        float sm2[4] = {0, 0, 0, 0}, sq2[4] = {0, 0, 0, 0};
        float vout[8][4];
        #pragma unroll
        for (int t2 = 0; t2 < 8; t2++)
            #pragma unroll
            for (int i = 0; i < 4; i++) {
                float v = acc2[t2][i] + sP[768 + t2 * 16 + c];
                if (resid) v += rr[t2][i];
                vout[t2][i] = v; sm2[i] += v; sq2[i] += v * v;
            }
        #pragma unroll
        for (int i = 0; i < 4; i++)
            #pragma unroll
            for (int m = 1; m < 16; m <<= 1) { sm2[i] += __shfl_xor(sm2[i], m, 64); sq2[i] += __shfl_xor(sq2[i], m, 64); }
        float mean2[4], rs2[4];
        #pragma unroll
        for (int i = 0; i < 4; i++) {
            mean2[i] = sm2[i] * (1.f / 128.f);
            float var = fmaxf(sq2[i] * (1.f / 128.f) - mean2[i] * mean2[i], 0.f);
            rs2[i] = rsqrtf(var + EPS_LN);
        }
        if (!do_pool) {
            #pragma unroll
            for (int t2 = 0; t2 < 8; t2++)
                #pragma unroll
                for (int i = 0; i < 4; i++) {
                    int col = t2 * 16 + c;
                    size_t idx = (size_t)nr[i] * 128 + col;
                    float v = vout[t2][i];
                    h[idx] = v;                                   // residual for next layer
                    float o = sP[896 + col] * (v - mean2[i]) * rs2[i] + sP[1024 + col];
                    h2_out[idx] = f2bf(fmaxf(o, 0.f));            // next conv input
                }
        } else {
            int bg[4];
            #pragma unroll
            for (int i = 0; i < 4; i++) bg[i] = batch[nr[i]];
            #pragma unroll
            for (int t2 = 0; t2 < 8; t2++)
                #pragma unroll
                for (int i = 0; i < 4; i++) {
                    int col = t2 * 16 + c;
                    float o = sP[896 + col] * (vout[t2][i] - mean2[i]) * rs2[i] + sP[1024 + col];
                    unsafeAtomicAdd(&pool[(size_t)bg[i] * 128 + col], o);
                }
            if (c == 0)
                #pragma unroll
                for (int i = 0; i < 4; i++) unsafeAtomicAdd(&cnt[bg[i]], 1.f);
        }
    }
}

// =============== readout: sigmoid(mean_pool @ Wp + bp) ===============
__global__ __launch_bounds__(64) void k_read(const float* __restrict__ pool,
                                             const float* __restrict__ cnt,
                                             const float* __restrict__ Wp,
                                             const float* __restrict__ bp,
                                             float* __restrict__ out) {
    int g = blockIdx.x, lane = threadIdx.x;
    float inv = 1.f / fmaxf(cnt[g], 1.f);
    float d = (pool[(size_t)g * 128 + lane] * Wp[lane] +
               pool[(size_t)g * 128 + 64 + lane] * Wp[64 + lane]) * inv;
    float s = wave_sum(d);
    if (lane == 0) out[g] = 1.f / (1.f + expf(-(s + bp[0])));
}

extern "C" void kernel_launch(void* const* d_in, const int* in_sizes, int n_in,
                              void* d_out, int out_size, void* d_ws, size_t ws_size,
                              hipStream_t stream) {
    const float* x   = (const float*)d_in[0];
    const int*   ei  = (const int*)d_in[1];
    const int*   ea  = (const int*)d_in[2];
    const int*   bat = (const int*)d_in[3];
    const float* We  = (const float*)d_in[4];
    const float* be  = (const float*)d_in[5];
    const float* Et  = (const float*)d_in[6];
    const float* W1  = (const float*)d_in[7];
    const float* b1  = (const float*)d_in[8];
    const float* g1  = (const float*)d_in[9];
    const float* bb1 = (const float*)d_in[10];
    const float* W2  = (const float*)d_in[11];
    const float* b2  = (const float*)d_in[12];
    const float* gn  = (const float*)d_in[13];
    const float* bn  = (const float*)d_in[14];
    const float* Wp  = (const float*)d_in[15];
    const float* bp  = (const float*)d_in[16];
    float* out = (float*)d_out;

    char* w = (char*)d_ws;
    float* h    = (float*)w;  w += (size_t)N_NODES * 128 * 4;
    u16*   h2a  = (u16*)w;    w += (size_t)N_NODES * 128 * 2;
    u16*   h2b  = (u16*)w;    w += (size_t)N_NODES * 128 * 2;
    u16*   w1t  = (u16*)w;    w += (size_t)4 * 32768 * 2;
    u16*   w2t  = (u16*)w;    w += (size_t)4 * 32768 * 2;
    float* pool = (float*)w;  w += (size_t)NGRAPH * 128 * 4;
    float* cnt  = (float*)w;  w += (size_t)NGRAPH * 4;
    int*   deg  = (int*)w;    w += (size_t)N_NODES * 4;
    int*   offs = (int*)w;    w += (size_t)N_NODES * 4;
    int*   curs = (int*)w;    w += (size_t)N_NODES * 4;
    int*   bsum = (int*)w;    w += 128 * 4;
    int*   csr  = (int*)w;    w += (size_t)N_EDGES * 4;
    int*   perm = (int*)w;    w += (size_t)N_NODES * 4;
    int*   dhist= (int*)w;    w += 64 * 4;

    const int NB_SCAN = (N_NODES + 1023) / 1024;   // 98

    hipMemsetAsync(pool, 0, ((size_t)NGRAPH * 128 + NGRAPH) * 4, stream);
    hipMemsetAsync(deg, 0, (size_t)N_NODES * 4, stream);
    hipMemsetAsync(dhist, 0, 64 * 4, stream);
    // weight pre-convert (once) + CSR build + degree bucket-sort (edges static)
    k_wconv<<<1024, 256, 0, stream>>>(W1, W2, w1t, w2t);
    k_hist<<<(N_EDGES + 255) / 256, 256, 0, stream>>>(ei, deg);
    k_dhist<<<(N_NODES + 255) / 256, 256, 0, stream>>>(deg, dhist);
    k_dscan<<<1, 64, 0, stream>>>(dhist);
    k_dplace<<<(N_NODES + 255) / 256, 256, 0, stream>>>(deg, dhist, perm);
    k_scan1<<<NB_SCAN, 256, 0, stream>>>(deg, offs, bsum);
    k_scan2<<<1, 128, 0, stream>>>(bsum, NB_SCAN);
    k_scan3<<<NB_SCAN, 256, 0, stream>>>(offs, bsum, curs);
    k_scatter<<<(N_EDGES + 255) / 256, 256, 0, stream>>>(ei, ea, curs, csr);

    k_enc<<<256, 256, 0, stream>>>(x, We, be, h2a);
    for (int l = 0; l < 4; l++) {
        const u16* hin = (l & 1) ? h2b : h2a;      // ping-pong: no RAW hazard on h2
        u16*       hout = (l & 1) ? h2a : h2b;
        k_fused<<<256, 512, 0, stream>>>(hin, h,
                                         w1t + (size_t)l * 32768, b1 + l * 256,
                                         g1 + l * 256, bb1 + l * 256,
                                         w2t + (size_t)l * 32768, b2 + l * 128,
                                         gn + l * 128, bn + l * 128,
                                         hout, bat, offs, deg, csr, Et, perm,
                                         pool, cnt,
                                         l > 0 ? 1 : 0, l == 3 ? 1 : 0);
    }
    k_read<<<NGRAPH, 64, 0, stream>>>(pool, cnt, Wp, bp, out);
}

// Round 14
// 772.905 us; speedup vs baseline: 1.6886x; 1.6886x over previous
//
#include <hip/hip_runtime.h>

#define N_NODES 100000
#define N_EDGES 600000
#define NGRAPH 512
#define NOPS_T 8
#define EPS_MSG 1e-7f
#define EPS_LN 1e-5f

typedef unsigned short u16;
typedef unsigned int u32;
typedef __attribute__((ext_vector_type(8))) short short8;   // 8 bf16 (4 VGPRs) MFMA A/B frag
typedef __attribute__((ext_vector_type(4))) float f32x4;    // MFMA C/D frag

__device__ __forceinline__ float bf2f(u16 u) {
    union { float f; u32 i; } v; v.i = ((u32)u) << 16; return v.f;
}
__device__ __forceinline__ u16 f2bf(float f) {
    union { float f; u32 i; } v; v.f = f;
    u32 r = (v.i + 0x7fffu + ((v.i >> 16) & 1u)) >> 16;   // RNE
    return (u16)r;
}
__device__ __forceinline__ float wave_sum(float v) {
    #pragma unroll
    for (int off = 32; off > 0; off >>= 1) v += __shfl_xor(v, off, 64);
    return v;
}

// =============== encoder: h2 = bf16(x @ We + be) ===============
__global__ __launch_bounds__(256, 1) void k_enc(const float* __restrict__ x,
                                                const float* __restrict__ We,
                                                const float* __restrict__ be,
                                                u16* __restrict__ h2) {
    __shared__ __align__(16) u16 sWe[128 * 136];   // We^T padded (+8): row n, k contiguous
    __shared__ float sB[128];
    int tid = threadIdx.x;
    for (int i = tid; i < 128 * 128; i += 256) { int k = i >> 7, n = i & 127; sWe[n * 136 + k] = f2bf(We[i]); }
    if (tid < 128) sB[tid] = be[tid];
    __syncthreads();
    int wave = tid >> 6, lane = tid & 63, q = lane >> 4, c = lane & 15;
    for (int tile = blockIdx.x * 4 + wave; tile < N_NODES / 16; tile += gridDim.x * 4) {
        int n0 = tile * 16;
        const float4* xp = (const float4*)(x + (size_t)(n0 + c) * 128);
        short8 af[4];
        #pragma unroll
        for (int ks = 0; ks < 4; ks++) {
            float4 v0 = xp[ks * 8 + q * 2], v1 = xp[ks * 8 + q * 2 + 1];
            short8 a;
            a[0] = (short)f2bf(v0.x); a[1] = (short)f2bf(v0.y);
            a[2] = (short)f2bf(v0.z); a[3] = (short)f2bf(v0.w);
            a[4] = (short)f2bf(v1.x); a[5] = (short)f2bf(v1.y);
            a[6] = (short)f2bf(v1.z); a[7] = (short)f2bf(v1.w);
            af[ks] = a;
        }
        f32x4 acc[8];
        #pragma unroll
        for (int t = 0; t < 8; t++) {
            f32x4 a4 = {0.f, 0.f, 0.f, 0.f};
            const short8* bp = (const short8*)(sWe + (t * 16 + c) * 136);
            #pragma unroll
            for (int ks = 0; ks < 4; ks++)
                a4 = __builtin_amdgcn_mfma_f32_16x16x32_bf16(af[ks], bp[ks * 4 + q], a4, 0, 0, 0);
            acc[t] = a4;
        }
        u16* h2b = h2 + (size_t)n0 * 128;
        #pragma unroll
        for (int t = 0; t < 8; t++)
            #pragma unroll
            for (int i = 0; i < 4; i++) {
                int idx = (q * 4 + i) * 128 + t * 16 + c;     // D: row=q*4+i, col=t*16+c
                h2b[idx] = f2bf(acc[t][i] + sB[t * 16 + c]);
            }
    }
}

// =============== weight pre-convert: fp32 -> bf16 transposed (n-major, k-contig) ===============
__global__ __launch_bounds__(256) void k_wconv(const float* __restrict__ W1,
                                               const float* __restrict__ W2,
                                               u16* __restrict__ w1t,
                                               u16* __restrict__ w2t) {
    int b = blockIdx.x, t = threadIdx.x;
    if (b < 512) {
        int idx = b * 256 + t;                           // over [4][256][128]
        int l = idx >> 15, r = idx & 32767, n = r >> 7, k = r & 127;
        w1t[idx] = f2bf(W1[(l << 15) + k * 256 + n]);
    } else {
        int idx = (b - 512) * 256 + t;                   // over [4][128][256]
        int l = idx >> 15, r = idx & 32767, n = r >> 8, k = r & 255;
        w2t[idx] = f2bf(W2[(l << 15) + k * 128 + n]);
    }
}

// =============== CSR build (once per launch; edges static across layers) ===============
__global__ __launch_bounds__(256) void k_hist(const int* __restrict__ ei, int* __restrict__ deg) {
    int e = blockIdx.x * 256 + threadIdx.x;
    if (e < N_EDGES) atomicAdd(&deg[ei[N_EDGES + e]], 1);
}

__global__ __launch_bounds__(256) void k_scan1(const int* __restrict__ deg,
                                               int* __restrict__ offs,
                                               int* __restrict__ bsum) {
    __shared__ int swv[4];
    int b = blockIdx.x, t = threadIdx.x;
    int base = b * 1024 + t * 4;
    int4 v = {0, 0, 0, 0};
    if (base < N_NODES) v = *(const int4*)(deg + base);   // N_NODES % 4 == 0
    int s = v.x + v.y + v.z + v.w;
    int lane = t & 63, wid = t >> 6;
    int incl = s;
    #pragma unroll
    for (int off = 1; off < 64; off <<= 1) {
        int o = __shfl_up(incl, off, 64);
        if (lane >= off) incl += o;
    }
    if (lane == 63) swv[wid] = incl;
    __syncthreads();
    int wbase = 0;
    #pragma unroll
    for (int w = 0; w < 4; w++) if (w < wid) wbase += swv[w];
    int ex = wbase + incl - s;
    if (base < N_NODES) {
        offs[base]     = ex;
        offs[base + 1] = ex + v.x;
        offs[base + 2] = ex + v.x + v.y;
        offs[base + 3] = ex + v.x + v.y + v.z;
    }
    if (t == 255) bsum[b] = wbase + incl;
}

__global__ __launch_bounds__(128) void k_scan2(int* __restrict__ bsum, int nb) {
    __shared__ int s[128];
    int t = threadIdx.x;
    int v = t < nb ? bsum[t] : 0;
    s[t] = v;
    __syncthreads();
    for (int off = 1; off < 128; off <<= 1) {
        int a = t >= off ? s[t - off] : 0;
        __syncthreads();
        s[t] += a;
        __syncthreads();
    }
    if (t < nb) bsum[t] = s[t] - v;
}

__global__ __launch_bounds__(256) void k_scan3(int* __restrict__ offs,
                                               const int* __restrict__ bsum,
                                               int* __restrict__ cursor) {
    int b = blockIdx.x, t = threadIdx.x;
    int base = b * 1024 + t * 4;
    if (base >= N_NODES) return;
    int add = bsum[b];
    #pragma unroll
    for (int i = 0; i < 4; i++) {
        int o = offs[base + i] + add;
        offs[base + i] = o;
        cursor[base + i] = o;
    }
}

__global__ __launch_bounds__(256) void k_scatter(const int* __restrict__ ei,
                                                 const int* __restrict__ ea,
                                                 int* __restrict__ cursor,
                                                 int* __restrict__ csr) {
    int e = blockIdx.x * 256 + threadIdx.x;
    if (e >= N_EDGES) return;
    int s = ei[e], d = ei[N_EDGES + e], a = ea[e];
    int pos = atomicAdd(&cursor[d], 1);
    csr[pos] = s | (a << 24);                 // src < 2^17, attr < 8
}

// =============== fused layer: AGG + GEMM1 + LN + ReLU + GEMM2 (+resid) + epilogue ===============
// FINAL (verified 774.8/775.4 µs): aggregation fused in (xin round-trip and k_agg
// launches deleted; h2 ping-pong breaks the RAW hazard). Per tile, 4 lanes/node
// (q=0..3) gather that node's 32 A-fragment dims over its edge list (unroll-2);
// Et staged bf16 in LDS (attr-padded). Gather-phase waves overlap MFMA-phase waves
// on the CU. 512 thr, 1 block/CU, LDS 154.2 KB, no reg cap (2 waves/SIMD — proven
// hard ceiling: every 4-wave/SIMD attempt spilled — R4/R7/R11; degree-sorted tile
// assignment regressed via atomic-contended sort + scattered epilogue — R13).
__global__ __launch_bounds__(512, 1) void k_fused(
    const u16* __restrict__ h2_in, float* __restrict__ h,
    const u16* __restrict__ w1t, const float* __restrict__ b1,
    const float* __restrict__ g1, const float* __restrict__ bb1,
    const u16* __restrict__ w2t, const float* __restrict__ b2,
    const float* __restrict__ gno, const float* __restrict__ bno,
    u16* __restrict__ h2_out, const int* __restrict__ batch,
    const int* __restrict__ offs, const int* __restrict__ deg,
    const int* __restrict__ csr, const float* __restrict__ Et,
    float* __restrict__ pool, float* __restrict__ cnt,
    int resid, int do_pool) {
    __shared__ __align__(16) u16 sW1[256 * 136];   // W1^T: [n][k], +8 pad      69632 B
    __shared__ __align__(16) u16 sW2[128 * 264];   // W2^T: [n][k], +8 pad      67584 B
    __shared__ __align__(16) u16 sY[8][16 * 40];   // per-wave y staging        10240 B
    __shared__ __align__(16) u16 sEb[8 * 136];     // Et bf16, +8 pad            2176 B
    __shared__ float sP[1152];                     // b1|g1|bb1|b2|gno|bno       4608 B
    int tid = threadIdx.x;
    {   // vectorized weight staging (16B load -> ds_write_b128)
        const short8* w1v = (const short8*)w1t;    // chunk i = n*16 + kc
        for (int i = tid; i < 4096; i += 512) { int n = i >> 4, kc = i & 15; *((short8*)(sW1 + n * 136) + kc) = w1v[i]; }
        const short8* w2v = (const short8*)w2t;    // chunk i = n*32 + kc
        for (int i = tid; i < 4096; i += 512) { int n = i >> 5, kc = i & 31; *((short8*)(sW2 + n * 264) + kc) = w2v[i]; }
    }
    for (int i = tid; i < 1024; i += 512) { int a = i >> 7, d = i & 127; sEb[a * 136 + d] = f2bf(Et[i]); }
    if (tid < 256) { sP[tid] = b1[tid]; sP[256 + tid] = g1[tid]; sP[512 + tid] = bb1[tid]; }
    if (tid < 128) { sP[768 + tid] = b2[tid]; sP[896 + tid] = gno[tid]; sP[1024 + tid] = bno[tid]; }
    __syncthreads();

    int wave = tid >> 6, lane = tid & 63, q = lane >> 4, c = lane & 15;
    u16* yst = sY[wave];
    const int NT = N_NODES / 16;

    for (int tile = blockIdx.x * 8 + wave; tile < NT; tile += gridDim.x * 8) {
        int n0 = tile * 16;
        int n = n0 + c;
        // ---- fused aggregation: ag[ks][e] covers dims ks*32+q*8+e of node c ----
        float ag[4][8];
        {
            const short8* sp = (const short8*)(h2_in + (size_t)n * 128);
            #pragma unroll
            for (int ks = 0; ks < 4; ks++) {
                short8 sv = sp[ks * 4 + q];
                #pragma unroll
                for (int e = 0; e < 8; e++) ag[ks][e] = bf2f((u16)sv[e]);
            }
        }
        int st = offs[n], dgv = deg[n];
        int j = 0;
        for (; j + 1 < dgv; j += 2) {                 // unroll-2: two gathers in flight
            int p0 = csr[st + j], p1 = csr[st + j + 1];
            int s0 = p0 & 0xFFFFFF, a0 = ((u32)p0) >> 24;
            int s1 = p1 & 0xFFFFFF, a1 = ((u32)p1) >> 24;
            const short8* h0 = (const short8*)(h2_in + (size_t)s0 * 128);
            const short8* h1 = (const short8*)(h2_in + (size_t)s1 * 128);
            short8 hv0[4], hv1[4], ev0[4], ev1[4];
            #pragma unroll
            for (int ks = 0; ks < 4; ks++) {
                hv0[ks] = h0[ks * 4 + q];
                hv1[ks] = h1[ks * 4 + q];
                ev0[ks] = *(const short8*)(sEb + a0 * 136 + ks * 32 + q * 8);
                ev1[ks] = *(const short8*)(sEb + a1 * 136 + ks * 32 + q * 8);
            }
            #pragma unroll
            for (int ks = 0; ks < 4; ks++)
                #pragma unroll
                for (int e = 0; e < 8; e++) {
                    ag[ks][e] += fmaxf(bf2f((u16)hv0[ks][e]) + bf2f((u16)ev0[ks][e]), 0.f) + EPS_MSG;
                    ag[ks][e] += fmaxf(bf2f((u16)hv1[ks][e]) + bf2f((u16)ev1[ks][e]), 0.f) + EPS_MSG;
                }
        }
        if (j < dgv) {
            int p = csr[st + j];
            int s = p & 0xFFFFFF, a = ((u32)p) >> 24;
            const short8* h0 = (const short8*)(h2_in + (size_t)s * 128);
            #pragma unroll
            for (int ks = 0; ks < 4; ks++) {
                short8 hv = h0[ks * 4 + q];
                short8 ev = *(const short8*)(sEb + a * 136 + ks * 32 + q * 8);
                #pragma unroll
                for (int e = 0; e < 8; e++)
                    ag[ks][e] += fmaxf(bf2f((u16)hv[e]) + bf2f((u16)ev[e]), 0.f) + EPS_MSG;
            }
        }
        // ---- pack A fragments (bf16) ----
        short8 af[4];
        #pragma unroll
        for (int ks = 0; ks < 4; ks++) {
            short8 a;
            #pragma unroll
            for (int e = 0; e < 8; e++) a[e] = (short)f2bf(ag[ks][e]);
            af[ks] = a;
        }
        // ---- residual load (issues now; hides under GEMM1+LN1+GEMM2) ----
        float rr[8][4];
        float* hb = h + (size_t)n0 * 128;
        if (resid) {
            #pragma unroll
            for (int t2 = 0; t2 < 8; t2++)
                #pragma unroll
                for (int i = 0; i < 4; i++) rr[t2][i] = hb[(q * 4 + i) * 128 + t2 * 16 + c];
        } else {
            #pragma unroll
            for (int t2 = 0; t2 < 8; t2++)
                #pragma unroll
                for (int i = 0; i < 4; i++) rr[t2][i] = 0.f;
        }
        // ---- GEMM1 ----
        f32x4 acc[16];
        #pragma unroll
        for (int t = 0; t < 16; t++) {
            f32x4 a4 = {0.f, 0.f, 0.f, 0.f};
            const short8* bp = (const short8*)(sW1 + (t * 16 + c) * 136);
            #pragma unroll
            for (int ks = 0; ks < 4; ks++)
                a4 = __builtin_amdgcn_mfma_f32_16x16x32_bf16(af[ks], bp[ks * 4 + q], a4, 0, 0, 0);
            acc[t] = a4;
        }
        // ---- +b1, LN over 256, ReLU (in-register; rows live in one quad) ----
        float sm[4] = {0, 0, 0, 0}, sq[4] = {0, 0, 0, 0};
        #pragma unroll
        for (int t = 0; t < 16; t++)
            #pragma unroll
            for (int i = 0; i < 4; i++) {
                float v = acc[t][i] + sP[t * 16 + c];
                acc[t][i] = v; sm[i] += v; sq[i] += v * v;
            }
        #pragma unroll
        for (int i = 0; i < 4; i++)
            #pragma unroll
            for (int m = 1; m < 16; m <<= 1) { sm[i] += __shfl_xor(sm[i], m, 64); sq[i] += __shfl_xor(sq[i], m, 64); }
        float mean[4], rs[4];
        #pragma unroll
        for (int i = 0; i < 4; i++) {
            mean[i] = sm[i] * (1.f / 256.f);
            float var = fmaxf(sq[i] * (1.f / 256.f) - mean[i] * mean[i], 0.f);
            rs[i] = rsqrtf(var + EPS_LN);
        }
        #pragma unroll
        for (int t = 0; t < 16; t++)
            #pragma unroll
            for (int i = 0; i < 4; i++) {
                int nn = t * 16 + c;
                acc[t][i] = fmaxf(sP[256 + nn] * (acc[t][i] - mean[i]) * rs[i] + sP[512 + nn], 0.f);
            }
        // ---- GEMM2: 8 K=32 chunks, single-buffer; read m -> stage m+1 -> MFMA m ----
        f32x4 acc2[8];
        #pragma unroll
        for (int t2 = 0; t2 < 8; t2++) acc2[t2] = (f32x4){0.f, 0.f, 0.f, 0.f};
        #pragma unroll
        for (int tt = 0; tt < 2; tt++)
            #pragma unroll
            for (int i = 0; i < 4; i++)
                yst[(q * 4 + i) * 40 + tt * 16 + c] = f2bf(acc[tt][i]);
        #pragma unroll
        for (int m = 0; m < 8; m++) {
            short8 a2 = *(const short8*)(yst + c * 40 + q * 8);   // read chunk m
            if (m < 7) {   // stage chunk m+1 while chunk m computes
                #pragma unroll
                for (int tt = 0; tt < 2; tt++)
                    #pragma unroll
                    for (int i = 0; i < 4; i++)
                        yst[(q * 4 + i) * 40 + tt * 16 + c] = f2bf(acc[(m + 1) * 2 + tt][i]);
            }
            #pragma unroll
            for (int t2 = 0; t2 < 8; t2++) {
                const short8* bp2 = (const short8*)(sW2 + (t2 * 16 + c) * 264 + m * 32);
                acc2[t2] = __builtin_amdgcn_mfma_f32_16x16x32_bf16(a2, bp2[q], acc2[t2], 0, 0, 0);
            }
        }
        // ---- epilogue: +b2 (+resid), then LN over 128 ----
        float sm2[4] = {0, 0, 0, 0}, sq2[4] = {0, 0, 0, 0};
        float vout[8][4];
        #pragma unroll
        for (int t2 = 0; t2 < 8; t2++)
            #pragma unroll
            for (int i = 0; i < 4; i++) {
                float v = acc2[t2][i] + sP[768 + t2 * 16 + c];
                if (resid) v += rr[t2][i];
                vout[t2][i] = v; sm2[i] += v; sq2[i] += v * v;
            }
        #pragma unroll
        for (int i = 0; i < 4; i++)
            #pragma unroll
            for (int m = 1; m < 16; m <<= 1) { sm2[i] += __shfl_xor(sm2[i], m, 64); sq2[i] += __shfl_xor(sq2[i], m, 64); }
        float mean2[4], rs2[4];
        #pragma unroll
        for (int i = 0; i < 4; i++) {
            mean2[i] = sm2[i] * (1.f / 128.f);
            float var = fmaxf(sq2[i] * (1.f / 128.f) - mean2[i] * mean2[i], 0.f);
            rs2[i] = rsqrtf(var + EPS_LN);
        }
        if (!do_pool) {
            u16* h2b = h2_out + (size_t)n0 * 128;
            #pragma unroll
            for (int t2 = 0; t2 < 8; t2++)
                #pragma unroll
                for (int i = 0; i < 4; i++) {
                    int col = t2 * 16 + c, idx = (q * 4 + i) * 128 + col;
                    float v = vout[t2][i];
                    hb[idx] = v;                                  // residual for next layer
                    float o = sP[896 + col] * (v - mean2[i]) * rs2[i] + sP[1024 + col];
                    h2b[idx] = f2bf(fmaxf(o, 0.f));               // next conv input
                }
        } else {
            int bg[4];
            #pragma unroll
            for (int i = 0; i < 4; i++) bg[i] = batch[n0 + q * 4 + i];
            #pragma unroll
            for (int t2 = 0; t2 < 8; t2++)
                #pragma unroll
                for (int i = 0; i < 4; i++) {
                    int col = t2 * 16 + c;
                    float o = sP[896 + col] * (vout[t2][i] - mean2[i]) * rs2[i] + sP[1024 + col];
                    unsafeAtomicAdd(&pool[(size_t)bg[i] * 128 + col], o);
                }
            if (c == 0)
                #pragma unroll
                for (int i = 0; i < 4; i++) unsafeAtomicAdd(&cnt[bg[i]], 1.f);
        }
    }
}

// =============== readout: sigmoid(mean_pool @ Wp + bp) ===============
__global__ __launch_bounds__(64) void k_read(const float* __restrict__ pool,
                                             const float* __restrict__ cnt,
                                             const float* __restrict__ Wp,
                                             const float* __restrict__ bp,
                                             float* __restrict__ out) {
    int g = blockIdx.x, lane = threadIdx.x;
    float inv = 1.f / fmaxf(cnt[g], 1.f);
    float d = (pool[(size_t)g * 128 + lane] * Wp[lane] +
               pool[(size_t)g * 128 + 64 + lane] * Wp[64 + lane]) * inv;
    float s = wave_sum(d);
    if (lane == 0) out[g] = 1.f / (1.f + expf(-(s + bp[0])));
}

extern "C" void kernel_launch(void* const* d_in, const int* in_sizes, int n_in,
                              void* d_out, int out_size, void* d_ws, size_t ws_size,
                              hipStream_t stream) {
    const float* x   = (const float*)d_in[0];
    const int*   ei  = (const int*)d_in[1];
    const int*   ea  = (const int*)d_in[2];
    const int*   bat = (const int*)d_in[3];
    const float* We  = (const float*)d_in[4];
    const float* be  = (const float*)d_in[5];
    const float* Et  = (const float*)d_in[6];
    const float* W1  = (const float*)d_in[7];
    const float* b1  = (const float*)d_in[8];
    const float* g1  = (const float*)d_in[9];
    const float* bb1 = (const float*)d_in[10];
    const float* W2  = (const float*)d_in[11];
    const float* b2  = (const float*)d_in[12];
    const float* gn  = (const float*)d_in[13];
    const float* bn  = (const float*)d_in[14];
    const float* Wp  = (const float*)d_in[15];
    const float* bp  = (const float*)d_in[16];
    float* out = (float*)d_out;

    char* w = (char*)d_ws;
    float* h    = (float*)w;  w += (size_t)N_NODES * 128 * 4;
    u16*   h2a  = (u16*)w;    w += (size_t)N_NODES * 128 * 2;
    u16*   h2b  = (u16*)w;    w += (size_t)N_NODES * 128 * 2;
    u16*   w1t  = (u16*)w;    w += (size_t)4 * 32768 * 2;
    u16*   w2t  = (u16*)w;    w += (size_t)4 * 32768 * 2;
    float* pool = (float*)w;  w += (size_t)NGRAPH * 128 * 4;
    float* cnt  = (float*)w;  w += (size_t)NGRAPH * 4;
    int*   deg  = (int*)w;    w += (size_t)N_NODES * 4;
    int*   offs = (int*)w;    w += (size_t)N_NODES * 4;
    int*   curs = (int*)w;    w += (size_t)N_NODES * 4;
    int*   bsum = (int*)w;    w += 128 * 4;
    int*   csr  = (int*)w;    w += (size_t)N_EDGES * 4;

    const int NB_SCAN = (N_NODES + 1023) / 1024;   // 98

    hipMemsetAsync(pool, 0, ((size_t)NGRAPH * 128 + NGRAPH) * 4, stream);
    hipMemsetAsync(deg, 0, (size_t)N_NODES * 4, stream);
    // weight pre-convert (once) + CSR build (edges static across layers)
    k_wconv<<<1024, 256, 0, stream>>>(W1, W2, w1t, w2t);
    k_hist<<<(N_EDGES + 255) / 256, 256, 0, stream>>>(ei, deg);
    k_scan1<<<NB_SCAN, 256, 0, stream>>>(deg, offs, bsum);
    k_scan2<<<1, 128, 0, stream>>>(bsum, NB_SCAN);
    k_scan3<<<NB_SCAN, 256, 0, stream>>>(offs, bsum, curs);
    k_scatter<<<(N_EDGES + 255) / 256, 256, 0, stream>>>(ei, ea, curs, csr);

    k_enc<<<256, 256, 0, stream>>>(x, We, be, h2a);
    for (int l = 0; l < 4; l++) {
        const u16* hin = (l & 1) ? h2b : h2a;      // ping-pong: no RAW hazard on h2
        u16*       hout = (l & 1) ? h2a : h2b;
        k_fused<<<256, 512, 0, stream>>>(hin, h,
                                         w1t + (size_t)l * 32768, b1 + l * 256,
                                         g1 + l * 256, bb1 + l * 256,
                                         w2t + (size_t)l * 32768, b2 + l * 128,
                                         gn + l * 128, bn + l * 128,
                                         hout, bat, offs, deg, csr, Et,
                                         pool, cnt,
                                         l > 0 ? 1 : 0, l == 3 ? 1 : 0);
    }
    k_read<<<NGRAPH, 64, 0, stream>>>(pool, cnt, Wp, bp, out);
}